// Round 2
// baseline (3033.834 us; speedup 1.0000x reference)
//
#include <hip/hip_runtime.h>

typedef __attribute__((ext_vector_type(8))) short s16x8;
typedef __attribute__((ext_vector_type(4))) short s16x4;
typedef __attribute__((ext_vector_type(4))) float f32x4;
typedef __attribute__((ext_vector_type(4))) unsigned int u32x4;

__device__ __forceinline__ short f2bf(float f) {
  unsigned u = __float_as_uint(f);
  u += 0x7fffu + ((u >> 16) & 1u);
  return (short)(u >> 16);
}
__device__ __forceinline__ float bf2f(short s) {
  return __uint_as_float(((unsigned)(unsigned short)s) << 16);
}
__device__ __forceinline__ float lo16f(unsigned u) { return __uint_as_float(u << 16); }
__device__ __forceinline__ float hi16f(unsigned u) { return __uint_as_float(u & 0xffff0000u); }
__device__ __forceinline__ float hswish(float v) { return v * fminf(fmaxf(v + 3.f, 0.f), 6.f) * (1.f / 6.f); }
__device__ __forceinline__ int iabs(int v) { return v < 0 ? -v : v; }

// ---------------- GEMM: out[M,N] = epi(A[M,K] @ W[N,K]^T) ----------------
// 128x128 tile, 4 waves (2x2), 16x16x32 bf16 MFMA, BK=64, reg-staged LDS with
// XOR swizzle (byte ^= (row&7)<<4) applied identically on write and read.
// RES: add split-bf16 residual (row stride 2N, hi@cn, lo@cn+N).
// WF: write f32 (stride N). WB: write plain bf16 (stride N).
// WS: write split bf16 (stride 2N, hi@cn, lo@cn+N).
template <int ACT, int RES, int WF, int WB, int WS>
__global__ __launch_bounds__(256) void gemm_k(
    const short* __restrict__ A, const short* __restrict__ W,
    const float* __restrict__ sc, const float* __restrict__ tc,
    const short* __restrict__ Rs, float* __restrict__ oF,
    short* __restrict__ oB, short* __restrict__ oS,
    int M, int N, int K) {
  __shared__ __align__(16) short As[128 * 64];
  __shared__ __align__(16) short Bs[128 * 64];
  const int tid = threadIdx.x;
  const int lane = tid & 63;
  const int wave = tid >> 6;
  const int wm = wave >> 1, wn = wave & 1;
  const int r15 = lane & 15, kq = lane >> 4;
  const int MT = M >> 7;
  const int mt = blockIdx.x % MT, nt = blockIdx.x / MT;
  const int m0 = mt << 7, n0 = nt << 7;

  f32x4 acc[4][4] = {};

  const int NT = K >> 6;
  s16x8 ra[4], rb[4];
#pragma unroll
  for (int i = 0; i < 4; ++i) {
    int c = i * 256 + tid;
    int row = c >> 3, col = (c & 7) << 3;
    ra[i] = *(const s16x8*)(A + (size_t)(m0 + row) * K + col);
    rb[i] = *(const s16x8*)(W + (size_t)(n0 + row) * K + col);
  }
  for (int kt = 0; kt < NT; ++kt) {
    __syncthreads();
#pragma unroll
    for (int i = 0; i < 4; ++i) {
      int c = i * 256 + tid;
      int byt = (c << 4) ^ (((c >> 3) & 7) << 4);
      *(s16x8*)((char*)As + byt) = ra[i];
      *(s16x8*)((char*)Bs + byt) = rb[i];
    }
    __syncthreads();
    if (kt + 1 < NT) {
      int k0 = (kt + 1) << 6;
#pragma unroll
      for (int i = 0; i < 4; ++i) {
        int c = i * 256 + tid;
        int row = c >> 3, col = (c & 7) << 3;
        ra[i] = *(const s16x8*)(A + (size_t)(m0 + row) * K + k0 + col);
        rb[i] = *(const s16x8*)(W + (size_t)(n0 + row) * K + k0 + col);
      }
    }
#pragma unroll
    for (int s = 0; s < 2; ++s) {
      s16x8 af[4], bq[4];
      const int cb = s * 64 + kq * 16;  // byte offset of k-chunk within a row
#pragma unroll
      for (int f = 0; f < 4; ++f) {
        int rowA = wm * 64 + f * 16 + r15;
        int bytA = (rowA * 128 + cb) ^ ((rowA & 7) << 4);
        af[f] = *(const s16x8*)((const char*)As + bytA);
        int rowB = wn * 64 + f * 16 + r15;
        int bytB = (rowB * 128 + cb) ^ ((rowB & 7) << 4);
        bq[f] = *(const s16x8*)((const char*)Bs + bytB);
      }
#pragma unroll
      for (int fm = 0; fm < 4; ++fm)
#pragma unroll
        for (int fn = 0; fn < 4; ++fn)
          acc[fm][fn] = __builtin_amdgcn_mfma_f32_16x16x32_bf16(af[fm], bq[fn], acc[fm][fn], 0, 0, 0);
    }
  }
#pragma unroll
  for (int fn = 0; fn < 4; ++fn) {
    const int cn = n0 + wn * 64 + fn * 16 + r15;
    const float scl = sc[cn], tcl = tc[cn];
#pragma unroll
    for (int fm = 0; fm < 4; ++fm) {
#pragma unroll
      for (int j = 0; j < 4; ++j) {
        const int rm = m0 + wm * 64 + fm * 16 + kq * 4 + j;
        float v = acc[fm][fn][j] * scl + tcl;
        if (ACT) v = hswish(v);
        if (RES) {
          const short* rp = Rs + (size_t)rm * (2 * N) + cn;
          v += bf2f(rp[0]) + bf2f(rp[N]);
        }
        if (WF) oF[(size_t)rm * N + cn] = v;
        if (WB) oB[(size_t)rm * N + cn] = f2bf(v);
        if (WS) {
          short h = f2bf(v);
          short l = f2bf(v - bf2f(h));
          short* sp = oS + (size_t)rm * (2 * N) + cn;
          sp[0] = h;
          sp[N] = l;
        }
      }
    }
  }
}

// q-dot-k over 32 dims, k-row in LDS as bf16 bit patterns
__device__ __forceinline__ float dotq(const float* qs, const short* kr) {
  float a = 0.f;
#pragma unroll
  for (int c = 0; c < 4; ++c) {
    u32x4 w = *(const u32x4*)(kr + c * 8);
#pragma unroll
    for (int e = 0; e < 4; ++e) {
      a += qs[c * 8 + e * 2] * lo16f(w[e]);
      a += qs[c * 8 + e * 2 + 1] * hi16f(w[e]);
    }
  }
  return a;
}

// ---------------- layer attention: 14x14, H1=4, d=32, v=64 ----------------
__global__ __launch_bounds__(256) void attn_k(const short* __restrict__ QKV,
                                              const float* __restrict__ bias,
                                              short* __restrict__ O) {
  const int b = blockIdx.x >> 2, h = blockIdx.x & 3;
  __shared__ __align__(16) short KV[196 * 96];
  __shared__ float Bsh[196];
  const int tid = threadIdx.x;
  const short* base = QKV + (size_t)b * (196 * 512);
  for (int c = tid; c < 196 * 12; c += 256) {
    int row = c / 12, ch = c - row * 12;
    *(s16x8*)&KV[row * 96 + ch * 8] =
        *(const s16x8*)(base + (size_t)row * 512 + h * 128 + 32 + ch * 8);
  }
  if (tid < 196) Bsh[tid] = bias[h * 196 + tid];
  __syncthreads();
  if (tid >= 196) return;
  const int q = tid;
  const int qi = q / 14, qj = q - qi * 14;
  float qs[32];
  {
    const short* qp = base + (size_t)q * 512 + h * 128;
#pragma unroll
    for (int c = 0; c < 4; ++c) {
      u32x4 w = *(const u32x4*)(qp + c * 8);
#pragma unroll
      for (int e = 0; e < 4; ++e) {
        qs[c * 8 + e * 2] = lo16f(w[e]) * 0.17677669529663687f;
        qs[c * 8 + e * 2 + 1] = hi16f(w[e]) * 0.17677669529663687f;
      }
    }
  }
  float mx = -1e30f;
  {
    int ki = 0, kj = 0;
    for (int k = 0; k < 196; ++k) {
      float lg = dotq(qs, &KV[k * 96]) + Bsh[iabs(qi - ki) * 14 + iabs(qj - kj)];
      mx = fmaxf(mx, lg);
      if (++kj == 14) { kj = 0; ++ki; }
    }
  }
  float o[64];
#pragma unroll
  for (int d = 0; d < 64; ++d) o[d] = 0.f;
  float lsum = 0.f;
  {
    int ki = 0, kj = 0;
    for (int k = 0; k < 196; ++k) {
      const short* kr = &KV[k * 96];
      float lg = dotq(qs, kr) + Bsh[iabs(qi - ki) * 14 + iabs(qj - kj)];
      float p = __expf(lg - mx);
      lsum += p;
#pragma unroll
      for (int c = 0; c < 8; ++c) {
        u32x4 w = *(const u32x4*)(kr + 32 + c * 8);
#pragma unroll
        for (int e = 0; e < 4; ++e) {
          o[c * 8 + e * 2] += p * lo16f(w[e]);
          o[c * 8 + e * 2 + 1] += p * hi16f(w[e]);
        }
      }
      if (++kj == 14) { kj = 0; ++ki; }
    }
  }
  const float inv = 1.f / lsum;
  short* op = O + (size_t)(b * 196 + q) * 256 + h * 64;
#pragma unroll
  for (int c = 0; c < 8; ++c) {
    s16x8 pk;
#pragma unroll
    for (int e = 0; e < 8; ++e) pk[e] = f2bf(hswish(o[c * 8 + e] * inv));
    *(s16x8*)(op + c * 8) = pk;
  }
}

// -------- subsample attention: q 7x7 (49), k 14x14 (196), H2=8, d=32, v=128 --------
__global__ __launch_bounds__(256) void subattn_k(const short* __restrict__ KVg,
                                                 const short* __restrict__ Qg,
                                                 const float* __restrict__ bias,
                                                 short* __restrict__ O2) {
  const int b = blockIdx.x >> 3, h = blockIdx.x & 7;
  __shared__ __align__(16) short KV[196 * 160];
  __shared__ float Bsh[196];
  const int tid = threadIdx.x;
  const short* base = KVg + (size_t)b * (196 * 1280) + h * 160;
  for (int c = tid; c < 196 * 20; c += 256) {
    int row = c / 20, ch = c - row * 20;
    *(s16x8*)&KV[row * 160 + ch * 8] = *(const s16x8*)(base + (size_t)row * 1280 + ch * 8);
  }
  if (tid < 196) Bsh[tid] = bias[h * 196 + tid];
  __syncthreads();
  if (tid >= 196) return;
  const int q = tid >> 2, sub = tid & 3;
  const int qi = q / 7, qj = q - qi * 7;
  float qs[32];
  {
    const short* qp = Qg + (size_t)(b * 49 + q) * 256 + h * 32;
#pragma unroll
    for (int c = 0; c < 4; ++c) {
      u32x4 w = *(const u32x4*)(qp + c * 8);
#pragma unroll
      for (int e = 0; e < 4; ++e) {
        qs[c * 8 + e * 2] = lo16f(w[e]) * 0.17677669529663687f;
        qs[c * 8 + e * 2 + 1] = hi16f(w[e]) * 0.17677669529663687f;
      }
    }
  }
  float mx = -1e30f;
  {
    int ki = 0, kj = 0;
    for (int k = 0; k < 196; ++k) {
      float lg = dotq(qs, &KV[k * 160]) + Bsh[iabs(2 * qi - ki) * 14 + iabs(2 * qj - kj)];
      mx = fmaxf(mx, lg);
      if (++kj == 14) { kj = 0; ++ki; }
    }
  }
  float o[32];
#pragma unroll
  for (int d = 0; d < 32; ++d) o[d] = 0.f;
  float lsum = 0.f;
  {
    int ki = 0, kj = 0;
    for (int k = 0; k < 196; ++k) {
      const short* kr = &KV[k * 160];
      float lg = dotq(qs, kr) + Bsh[iabs(2 * qi - ki) * 14 + iabs(2 * qj - kj)];
      float p = __expf(lg - mx);
      lsum += p;
      const short* vr = kr + 32 + sub * 32;
#pragma unroll
      for (int c = 0; c < 4; ++c) {
        u32x4 w = *(const u32x4*)(vr + c * 8);
#pragma unroll
        for (int e = 0; e < 4; ++e) {
          o[c * 8 + e * 2] += p * lo16f(w[e]);
          o[c * 8 + e * 2 + 1] += p * hi16f(w[e]);
        }
      }
      if (++kj == 14) { kj = 0; ++ki; }
    }
  }
  const float inv = 1.f / lsum;
  short* op = O2 + (size_t)(b * 49 + q) * 1024 + h * 128 + sub * 32;
#pragma unroll
  for (int c = 0; c < 4; ++c) {
    s16x8 pk;
#pragma unroll
    for (int e = 0; e < 8; ++e) pk[e] = f2bf(hswish(o[c * 8 + e] * inv));
    *(s16x8*)(op + c * 8) = pk;
  }
}

// ---------------- utility kernels ----------------
__global__ void cast_k(const float* __restrict__ s, short* __restrict__ d, int n4) {
  int i = blockIdx.x * 256 + threadIdx.x;
  if (i >= n4) return;
  const float4 v = ((const float4*)s)[i];
  s16x4 r;
  r[0] = f2bf(v.x); r[1] = f2bf(v.y); r[2] = f2bf(v.z); r[3] = f2bf(v.w);
  ((s16x4*)d)[i] = r;
}

// cast f32 [rows,K] -> bf16 [rows,2K] with the row duplicated along K
__global__ void castdup_k(const float* __restrict__ s, short* __restrict__ d,
                          int K, int n4) {
  int i = blockIdx.x * 256 + threadIdx.x;
  if (i >= n4) return;
  int e0 = i * 4;
  int r = e0 / K;
  int c = e0 - r * K;
  const float4 v = *(const float4*)(s + e0);
  s16x4 p;
  p[0] = f2bf(v.x); p[1] = f2bf(v.y); p[2] = f2bf(v.z); p[3] = f2bf(v.w);
  short* dr = d + (size_t)r * (2 * K) + c;
  *(s16x4*)dr = p;
  *(s16x4*)(dr + K) = p;
}

// f32 x (50176x256) -> split bf16 planes (row stride 512: hi|lo)
__global__ void initx_k(const float* __restrict__ x, short* __restrict__ Xs, int n4) {
  int i = blockIdx.x * 256 + threadIdx.x;
  if (i >= n4) return;
  int e0 = i * 4;
  int r = e0 >> 8, c = e0 & 255;
  const float4 v = *(const float4*)(x + e0);
  s16x4 h, l;
  h[0] = f2bf(v.x); l[0] = f2bf(v.x - bf2f(h[0]));
  h[1] = f2bf(v.y); l[1] = f2bf(v.y - bf2f(h[1]));
  h[2] = f2bf(v.z); l[2] = f2bf(v.z - bf2f(h[2]));
  h[3] = f2bf(v.w); l[3] = f2bf(v.w - bf2f(h[3]));
  short* dr = Xs + ((size_t)r << 9) + c;
  *(s16x4*)dr = h;
  *(s16x4*)(dr + 256) = l;
}

// gather strided 7x7 rows out of 14x14 (512 bf16 per split row, 64 chunks)
__global__ void gather_k(const short* __restrict__ Xs, short* __restrict__ Xq) {
  int idx = blockIdx.x * 256 + threadIdx.x;  // < 12544*64
  int r = idx >> 6, ch = idx & 63;
  int bb = r / 49, p = r - bb * 49;
  int i = p / 7, j = p - i * 7;
  int sr = bb * 196 + i * 28 + j * 2;
  *(s16x8*)(Xq + ((size_t)r << 9) + (ch << 3)) =
      *(const s16x8*)(Xs + ((size_t)sr << 9) + (ch << 3));
}

extern "C" void kernel_launch(void* const* d_in, const int* in_sizes, int n_in,
                              void* d_out, int out_size, void* d_ws, size_t ws_size,
                              hipStream_t stream) {
  (void)in_sizes; (void)n_in; (void)out_size; (void)ws_size;
  const float* x = (const float*)d_in[0];
  const float* Wqkv = (const float*)d_in[1];
  const float* qkvs = (const float*)d_in[2];
  const float* qkvt = (const float*)d_in[3];
  const float* Wproj = (const float*)d_in[4];
  const float* projs = (const float*)d_in[5];
  const float* projt = (const float*)d_in[6];
  const float* abias = (const float*)d_in[7];
  const float* W1 = (const float*)d_in[8];
  const float* m1s = (const float*)d_in[9];
  const float* m1t = (const float*)d_in[10];
  const float* W2 = (const float*)d_in[11];
  const float* m2s = (const float*)d_in[12];
  const float* m2t = (const float*)d_in[13];
  const float* Wkv = (const float*)d_in[14];
  const float* kvs = (const float*)d_in[15];
  const float* kvt = (const float*)d_in[16];
  const float* Wq = (const float*)d_in[17];
  const float* qss = (const float*)d_in[18];
  const float* qst = (const float*)d_in[19];
  const float* Wp2 = (const float*)d_in[20];
  const float* p2s = (const float*)d_in[21];
  const float* p2t = (const float*)d_in[22];
  const float* sbias = (const float*)d_in[23];
  const float* Ws1 = (const float*)d_in[24];
  const float* s1s = (const float*)d_in[25];
  const float* s1t = (const float*)d_in[26];
  const float* Ws2 = (const float*)d_in[27];
  const float* s2s = (const float*)d_in[28];
  const float* s2t = (const float*)d_in[29];

  char* ws = (char*)d_ws;
  short* WB = (short*)ws;  // bf16 weight arena (element offsets)
  short* WDqkv = WB;                  // 4 x (512x512)   dup
  short* WBproj = WB + 1048576;       // 4 x (256x256)
  short* WD1 = WB + 1310720;          // 4 x (512x512)   dup
  short* WD2 = WB + 2359296;          // 4 x (256x1024)  dup
  short* WDkv = WB + 3407872;         // 1280x512        dup
  short* WDq = WB + 4063232;          // 256x512         dup
  short* WBp2 = WB + 4194304;         // 384x1024
  short* WDs1 = WB + 4587520;         // 768x768         dup
  short* WDs2 = WB + 5177344;         // 384x1536        dup

  short* Xs = (short*)(ws + 11534336);    // 50176 x 512 split (hi|lo)
  char* arena = ws + 62914560;
  short* QKVb = (short*)arena;            // 50176x512
  short* Ob = (short*)(arena + 51380224); // 50176x256
  short* Hs = (short*)arena;              // 50176x1024 split
  short* KVb = (short*)arena;             // 50176x1280
  short* Xqs = (short*)(arena + 128450560);  // 12544x512 split
  short* Qb = (short*)(arena + 141295616);   // 12544x256
  short* O2b = Xs;                        // 12544x1024 (Xs dead by then)
  short* X2s = (short*)(ws + 11534336 + 25690112);  // 12544x768 split
  short* H2s = (short*)arena;             // 12544x1536 split (KVb dead)

  auto cast = [&](const float* s, short* d, int n) {
    int n4 = n >> 2;
    cast_k<<<dim3((n4 + 255) / 256), dim3(256), 0, stream>>>(s, d, n4);
  };
  auto castdup = [&](const float* s, short* d, int rows, int K) {
    int n4 = (rows * K) >> 2;
    castdup_k<<<dim3((n4 + 255) / 256), dim3(256), 0, stream>>>(s, d, K, n4);
  };
  castdup(Wqkv, WDqkv, 2048, 256);
  cast(Wproj, WBproj, 262144);
  castdup(W1, WD1, 2048, 256);
  castdup(W2, WD2, 1024, 512);
  castdup(Wkv, WDkv, 1280, 256);
  castdup(Wq, WDq, 256, 256);
  cast(Wp2, WBp2, 393216);
  castdup(Ws1, WDs1, 768, 384);
  castdup(Ws2, WDs2, 384, 768);
  initx_k<<<12544, 256, 0, stream>>>(x, Xs, 3211264);

  for (int l = 0; l < 4; ++l) {
    gemm_k<0, 0, 0, 1, 0><<<392 * 4, 256, 0, stream>>>(
        Xs, WDqkv + l * 262144, qkvs + l * 512, qkvt + l * 512,
        nullptr, nullptr, QKVb, nullptr, 50176, 512, 512);
    attn_k<<<1024, 256, 0, stream>>>(QKVb, abias + l * 784, Ob);
    gemm_k<0, 1, 0, 0, 1><<<392 * 2, 256, 0, stream>>>(
        Ob, WBproj + l * 65536, projs + l * 256, projt + l * 256,
        Xs, nullptr, nullptr, Xs, 50176, 256, 256);
    gemm_k<1, 0, 0, 0, 1><<<392 * 4, 256, 0, stream>>>(
        Xs, WD1 + l * 262144, m1s + l * 512, m1t + l * 512,
        nullptr, nullptr, nullptr, Hs, 50176, 512, 512);
    gemm_k<0, 1, 0, 0, 1><<<392 * 2, 256, 0, stream>>>(
        Hs, WD2 + l * 262144, m2s + l * 256, m2t + l * 256,
        Xs, nullptr, nullptr, Xs, 50176, 256, 1024);
  }
  gemm_k<0, 0, 0, 1, 0><<<392 * 10, 256, 0, stream>>>(
      Xs, WDkv, kvs, kvt, nullptr, nullptr, KVb, nullptr, 50176, 1280, 512);
  gather_k<<<3136, 256, 0, stream>>>(Xs, Xqs);
  gemm_k<0, 0, 0, 1, 0><<<98 * 2, 256, 0, stream>>>(
      Xqs, WDq, qss, qst, nullptr, nullptr, Qb, nullptr, 12544, 256, 512);
  subattn_k<<<2048, 256, 0, stream>>>(KVb, Qb, sbias, O2b);
  gemm_k<0, 0, 0, 0, 1><<<98 * 3, 256, 0, stream>>>(
      O2b, WBp2, p2s, p2t, nullptr, nullptr, nullptr, X2s, 12544, 384, 1024);
  gemm_k<1, 0, 0, 0, 1><<<98 * 6, 256, 0, stream>>>(
      X2s, WDs1, s1s, s1t, nullptr, nullptr, nullptr, H2s, 12544, 768, 768);
  gemm_k<0, 1, 1, 0, 0><<<98 * 3, 256, 0, stream>>>(
      H2s, WDs2, s2s, s2t, X2s, (float*)d_out, nullptr, nullptr, 12544, 384, 1536);
}

// Round 4
// 1613.325 us; speedup vs baseline: 1.8805x; 1.8805x over previous
//
#include <hip/hip_runtime.h>

typedef __attribute__((ext_vector_type(8))) short s16x8;
typedef __attribute__((ext_vector_type(4))) short s16x4;
typedef __attribute__((ext_vector_type(4))) float f32x4;
typedef __attribute__((ext_vector_type(4))) unsigned int u32x4;
typedef __attribute__((ext_vector_type(8))) __fp16 f16x8;
typedef __attribute__((ext_vector_type(2))) __fp16 f16x2;

__device__ __forceinline__ short f2bf(float f) {
  unsigned u = __float_as_uint(f);
  u += 0x7fffu + ((u >> 16) & 1u);
  return (short)(u >> 16);
}
__device__ __forceinline__ float bf2f(short s) {
  return __uint_as_float(((unsigned)(unsigned short)s) << 16);
}
__device__ __forceinline__ float lo16f(unsigned u) { return __uint_as_float(u << 16); }
__device__ __forceinline__ float hi16f(unsigned u) { return __uint_as_float(u & 0xffff0000u); }
__device__ __forceinline__ float hswish(float v) { return v * fminf(fmaxf(v + 3.f, 0.f), 6.f) * (1.f / 6.f); }
__device__ __forceinline__ int iabs(int v) { return v < 0 ? -v : v; }
__device__ __forceinline__ unsigned pkh2(float a, float b) {
  f16x2 h = __builtin_amdgcn_cvt_pkrtz(a, b);
  return *(unsigned*)&h;
}

// ---------------- GEMM: out[M,N] = epi(A[M,K] @ W[N,K]^T) ----------------
template <int ACT, int RES, int WF, int WB, int WS>
__global__ __launch_bounds__(256) void gemm_k(
    const short* __restrict__ A, const short* __restrict__ W,
    const float* __restrict__ sc, const float* __restrict__ tc,
    const short* __restrict__ Rs, float* __restrict__ oF,
    short* __restrict__ oB, short* __restrict__ oS,
    int M, int N, int K) {
  __shared__ __align__(16) short As[128 * 64];
  __shared__ __align__(16) short Bs[128 * 64];
  const int tid = threadIdx.x;
  const int lane = tid & 63;
  const int wave = tid >> 6;
  const int wm = wave >> 1, wn = wave & 1;
  const int r15 = lane & 15, kq = lane >> 4;
  const int MT = M >> 7;
  const int mt = blockIdx.x % MT, nt = blockIdx.x / MT;
  const int m0 = mt << 7, n0 = nt << 7;

  f32x4 acc[4][4] = {};

  const int NT = K >> 6;
  s16x8 ra[4], rb[4];
#pragma unroll
  for (int i = 0; i < 4; ++i) {
    int c = i * 256 + tid;
    int row = c >> 3, col = (c & 7) << 3;
    ra[i] = *(const s16x8*)(A + (size_t)(m0 + row) * K + col);
    rb[i] = *(const s16x8*)(W + (size_t)(n0 + row) * K + col);
  }
  for (int kt = 0; kt < NT; ++kt) {
    __syncthreads();
#pragma unroll
    for (int i = 0; i < 4; ++i) {
      int c = i * 256 + tid;
      int byt = (c << 4) ^ (((c >> 3) & 7) << 4);
      *(s16x8*)((char*)As + byt) = ra[i];
      *(s16x8*)((char*)Bs + byt) = rb[i];
    }
    __syncthreads();
    if (kt + 1 < NT) {
      int k0 = (kt + 1) << 6;
#pragma unroll
      for (int i = 0; i < 4; ++i) {
        int c = i * 256 + tid;
        int row = c >> 3, col = (c & 7) << 3;
        ra[i] = *(const s16x8*)(A + (size_t)(m0 + row) * K + k0 + col);
        rb[i] = *(const s16x8*)(W + (size_t)(n0 + row) * K + k0 + col);
      }
    }
#pragma unroll
    for (int s = 0; s < 2; ++s) {
      s16x8 af[4], bq[4];
      const int cb = s * 64 + kq * 16;
#pragma unroll
      for (int f = 0; f < 4; ++f) {
        int rowA = wm * 64 + f * 16 + r15;
        int bytA = (rowA * 128 + cb) ^ ((rowA & 7) << 4);
        af[f] = *(const s16x8*)((const char*)As + bytA);
        int rowB = wn * 64 + f * 16 + r15;
        int bytB = (rowB * 128 + cb) ^ ((rowB & 7) << 4);
        bq[f] = *(const s16x8*)((const char*)Bs + bytB);
      }
#pragma unroll
      for (int fm = 0; fm < 4; ++fm)
#pragma unroll
        for (int fn = 0; fn < 4; ++fn)
          acc[fm][fn] = __builtin_amdgcn_mfma_f32_16x16x32_bf16(af[fm], bq[fn], acc[fm][fn], 0, 0, 0);
    }
  }
#pragma unroll
  for (int fn = 0; fn < 4; ++fn) {
    const int cn = n0 + wn * 64 + fn * 16 + r15;
    const float scl = sc[cn], tcl = tc[cn];
#pragma unroll
    for (int fm = 0; fm < 4; ++fm) {
#pragma unroll
      for (int j = 0; j < 4; ++j) {
        const int rm = m0 + wm * 64 + fm * 16 + kq * 4 + j;
        float v = acc[fm][fn][j] * scl + tcl;
        if (ACT) v = hswish(v);
        if (RES) {
          const short* rp = Rs + (size_t)rm * (2 * N) + cn;
          v += bf2f(rp[0]) + bf2f(rp[N]);
        }
        if (WF) oF[(size_t)rm * N + cn] = v;
        if (WB) oB[(size_t)rm * N + cn] = f2bf(v);
        if (WS) {
          short h = f2bf(v);
          short l = f2bf(v - bf2f(h));
          short* sp = oS + (size_t)rm * (2 * N) + cn;
          sp[0] = h;
          sp[N] = l;
        }
      }
    }
  }
}

// ---------------- MFMA attention (layer): S=196, d=32, v=64, H1=4 ----------------
// swapped QK^T: mfma(A=K, B=Q) -> lane owns full k-row for q = lane&15.
// P normalized -> fp16 -> LDS roundtrip -> PV with mfma_f16. V transposed fp16 in LDS.
__global__ __launch_bounds__(256) void attn_mfma_k(const short* __restrict__ QKV,
                                                   const float* __restrict__ bias,
                                                   short* __restrict__ O) {
  __shared__ __align__(16) short Vt[64 * 232];       // fp16 bits, [v][k], pad k->232
  __shared__ __align__(16) short P[4 * 16 * 232];    // fp16 bits, per wave [q][k]
  __shared__ float Bsh[196];
  const int b = blockIdx.x >> 2, h = blockIdx.x & 3;
  const int tid = threadIdx.x;
  const int lane = tid & 63, wave = tid >> 6;
  const int l15 = lane & 15, g = lane >> 4, g4 = g * 4;
  const short* base = QKV + (size_t)b * (196 * 512);

  // zero pads: Vt cols [196,232), P cols [208,232)
  for (int c = tid; c < 1152; c += 256) {
    int v = c / 18, u = c - v * 18;
    *((unsigned*)Vt + v * 116 + 98 + u) = 0;
  }
  for (int c = tid; c < 768; c += 256) {
    int r = c / 12, u = c - r * 12;
    *((unsigned*)P + r * 116 + 104 + u) = 0;
  }
  if (tid < 196) Bsh[tid] = bias[h * 196 + tid];
  // stage V transposed (fp16): Vt[v][k] = V[k][v]
  for (int c = tid; c < 3136; c += 256) {
    int vp = c & 31, kp = c >> 5;
    const short* s = base + (size_t)(2 * kp) * 512 + h * 128 + 64 + 2 * vp;
    unsigned a0 = *(const unsigned*)s;
    unsigned a1 = *(const unsigned*)(s + 512);
    unsigned p0 = pkh2(lo16f(a0), lo16f(a1));
    unsigned p1 = pkh2(hi16f(a0), hi16f(a1));
    *((unsigned*)Vt + (2 * vp) * 116 + kp) = p0;
    *((unsigned*)Vt + (2 * vp + 1) * 116 + kp) = p1;
  }
  __syncthreads();

  // K fragments in registers (shared across this wave's q-tiles)
  s16x8 kf[13];
  {
    const short* kb = base + h * 128 + 32 + 8 * g;
#pragma unroll
    for (int t = 0; t < 13; ++t) {
      int kr = 16 * t + l15;
      if (kr > 195) kr = 195;
      kf[t] = *(const s16x8*)(kb + (size_t)kr * 512);
    }
  }

  for (int qt = wave; qt < 13; qt += 4) {
    int qr = 16 * qt + l15;
    if (qr > 195) qr = 195;
    s16x8 qf = *(const s16x8*)(base + (size_t)qr * 512 + h * 128 + 8 * g);
    f32x4 s[13];
#pragma unroll
    for (int t = 0; t < 13; ++t)
      s[t] = __builtin_amdgcn_mfma_f32_16x16x32_bf16(kf[t], qf, f32x4{0.f, 0.f, 0.f, 0.f}, 0, 0, 0);

    const int q = 16 * qt + l15;
    const int qc = q > 195 ? 195 : q;
    const int qi = qc / 14, qj = qc - 14 * qi;
    float m = -1e30f;
#pragma unroll
    for (int t = 0; t < 13; ++t)
#pragma unroll
      for (int j = 0; j < 4; ++j) {
        int k = 16 * t + g4 + j;
        float v = -1e30f;
        if (k < 196) {
          int ki = k / 14, kj = k - 14 * ki;
          v = fmaf(s[t][j], 0.17677669529663687f, Bsh[iabs(qi - ki) * 14 + iabs(qj - kj)]);
        }
        s[t][j] = v;
        m = fmaxf(m, v);
      }
    m = fmaxf(m, __shfl_xor(m, 16));
    m = fmaxf(m, __shfl_xor(m, 32));
    float sum = 0.f;
#pragma unroll
    for (int t = 0; t < 13; ++t)
#pragma unroll
      for (int j = 0; j < 4; ++j) {
        float p = __expf(s[t][j] - m);
        s[t][j] = p;
        sum += p;
      }
    sum += __shfl_xor(sum, 16);
    sum += __shfl_xor(sum, 32);
    const float inv = 1.f / sum;
    unsigned* pw = (unsigned*)P + wave * (16 * 116) + l15 * 116;
#pragma unroll
    for (int t = 0; t < 13; ++t) {
      pw[8 * t + 2 * g] = pkh2(s[t][0] * inv, s[t][1] * inv);
      pw[8 * t + 2 * g + 1] = pkh2(s[t][2] * inv, s[t][3] * inv);
    }
    asm volatile("s_waitcnt lgkmcnt(0)" ::: "memory");

    f32x4 o[4] = {};
    const short* pr = P + wave * (16 * 232) + l15 * 232 + 8 * g;
    const short* vr = Vt + l15 * 232 + 8 * g;
#pragma unroll
    for (int kb = 0; kb < 7; ++kb) {
      f16x8 pa = *(const f16x8*)(pr + 32 * kb);
#pragma unroll
      for (int vt = 0; vt < 4; ++vt) {
        f16x8 vb = *(const f16x8*)(vr + vt * 16 * 232 + 32 * kb);
        o[vt] = __builtin_amdgcn_mfma_f32_16x16x32_f16(pa, vb, o[vt], 0, 0, 0);
      }
    }
#pragma unroll
    for (int vt = 0; vt < 4; ++vt)
#pragma unroll
      for (int j = 0; j < 4; ++j) {
        int qo = 16 * qt + g4 + j;
        if (qo < 196)
          O[(size_t)(b * 196 + qo) * 256 + h * 64 + vt * 16 + l15] = f2bf(hswish(o[vt][j]));
      }
  }
}

// -------- MFMA subsample attention: q=49(pad 64), k=196, d=32, v=128, H2=8 --------
__global__ __launch_bounds__(256) void subattn_mfma_k(const short* __restrict__ KVg,
                                                      const short* __restrict__ Qg,
                                                      const float* __restrict__ bias,
                                                      short* __restrict__ O2) {
  __shared__ __align__(16) short Vt[64 * 232];     // fp16, one 64-v chunk
  __shared__ __align__(16) short P[4 * 16 * 232];  // fp16
  __shared__ float Bsh[196];
  const int b = blockIdx.x >> 3, h = blockIdx.x & 7;
  const int tid = threadIdx.x;
  const int lane = tid & 63, wave = tid >> 6;
  const int l15 = lane & 15, g = lane >> 4, g4 = g * 4;
  const short* base = KVg + (size_t)b * (196 * 1280) + h * 160;

  for (int c = tid; c < 1152; c += 256) {
    int v = c / 18, u = c - v * 18;
    *((unsigned*)Vt + v * 116 + 98 + u) = 0;
  }
  for (int c = tid; c < 768; c += 256) {
    int r = c / 12, u = c - r * 12;
    *((unsigned*)P + r * 116 + 104 + u) = 0;
  }
  if (tid < 196) Bsh[tid] = bias[h * 196 + tid];

  // K frags in regs
  s16x8 kf[13];
#pragma unroll
  for (int t = 0; t < 13; ++t) {
    int kr = 16 * t + l15;
    if (kr > 195) kr = 195;
    kf[t] = *(const s16x8*)(base + (size_t)kr * 1280 + 8 * g);
  }

  f32x4 s[13];
  float inv;
  const int qt = wave;

  for (int half = 0; half < 2; ++half) {
    if (half) __syncthreads();  // all waves done with prev Vt chunk
    // stage Vt chunk (v in [64*half, 64*half+64))
    for (int c = tid; c < 3136; c += 256) {
      int vp = c & 31, kp = c >> 5;
      const short* sp = base + (size_t)(2 * kp) * 1280 + 32 + 64 * half + 2 * vp;
      unsigned a0 = *(const unsigned*)sp;
      unsigned a1 = *(const unsigned*)(sp + 1280);
      *((unsigned*)Vt + (2 * vp) * 116 + kp) = pkh2(lo16f(a0), lo16f(a1));
      *((unsigned*)Vt + (2 * vp + 1) * 116 + kp) = pkh2(hi16f(a0), hi16f(a1));
    }
    __syncthreads();

    if (half == 0) {
      int qr = 16 * qt + l15;  // q within padded 64; actual q = qr (<49 valid)
      int qc = qr > 48 ? 48 : qr;
      s16x8 qf = *(const s16x8*)(Qg + (size_t)(b * 49 + qc) * 256 + h * 32 + 8 * g);
#pragma unroll
      for (int t = 0; t < 13; ++t)
        s[t] = __builtin_amdgcn_mfma_f32_16x16x32_bf16(kf[t], qf, f32x4{0.f, 0.f, 0.f, 0.f}, 0, 0, 0);
      const int q = qc;
      const int qi = q / 7, qj = q - 7 * qi;
      float m = -1e30f;
#pragma unroll
      for (int t = 0; t < 13; ++t)
#pragma unroll
        for (int j = 0; j < 4; ++j) {
          int k = 16 * t + g4 + j;
          float v = -1e30f;
          if (k < 196) {
            int ki = k / 14, kj = k - 14 * ki;
            v = fmaf(s[t][j], 0.17677669529663687f,
                     Bsh[iabs(2 * qi - ki) * 14 + iabs(2 * qj - kj)]);
          }
          s[t][j] = v;
          m = fmaxf(m, v);
        }
      m = fmaxf(m, __shfl_xor(m, 16));
      m = fmaxf(m, __shfl_xor(m, 32));
      float sum = 0.f;
#pragma unroll
      for (int t = 0; t < 13; ++t)
#pragma unroll
        for (int j = 0; j < 4; ++j) {
          float p = __expf(s[t][j] - m);
          s[t][j] = p;
          sum += p;
        }
      sum += __shfl_xor(sum, 16);
      sum += __shfl_xor(sum, 32);
      inv = 1.f / sum;
      unsigned* pw = (unsigned*)P + wave * (16 * 116) + l15 * 116;
#pragma unroll
      for (int t = 0; t < 13; ++t) {
        pw[8 * t + 2 * g] = pkh2(s[t][0] * inv, s[t][1] * inv);
        pw[8 * t + 2 * g + 1] = pkh2(s[t][2] * inv, s[t][3] * inv);
      }
      asm volatile("s_waitcnt lgkmcnt(0)" ::: "memory");
    }

    f32x4 o[4] = {};
    const short* pr = P + wave * (16 * 232) + l15 * 232 + 8 * g;
    const short* vr = Vt + l15 * 232 + 8 * g;
#pragma unroll
    for (int kb = 0; kb < 7; ++kb) {
      f16x8 pa = *(const f16x8*)(pr + 32 * kb);
#pragma unroll
      for (int vt = 0; vt < 4; ++vt) {
        f16x8 vb = *(const f16x8*)(vr + vt * 16 * 232 + 32 * kb);
        o[vt] = __builtin_amdgcn_mfma_f32_16x16x32_f16(pa, vb, o[vt], 0, 0, 0);
      }
    }
#pragma unroll
    for (int vt = 0; vt < 4; ++vt)
#pragma unroll
      for (int j = 0; j < 4; ++j) {
        int qo = 16 * qt + g4 + j;
        if (qo < 49)
          O2[(size_t)(b * 49 + qo) * 1024 + h * 128 + half * 64 + vt * 16 + l15] =
              f2bf(hswish(o[vt][j]));
      }
  }
}

// ---------------- utility kernels ----------------
__global__ void cast_k(const float* __restrict__ s, short* __restrict__ d, int n4) {
  int i = blockIdx.x * 256 + threadIdx.x;
  if (i >= n4) return;
  const float4 v = ((const float4*)s)[i];
  s16x4 r;
  r[0] = f2bf(v.x); r[1] = f2bf(v.y); r[2] = f2bf(v.z); r[3] = f2bf(v.w);
  ((s16x4*)d)[i] = r;
}

__global__ void castdup_k(const float* __restrict__ s, short* __restrict__ d,
                          int K, int n4) {
  int i = blockIdx.x * 256 + threadIdx.x;
  if (i >= n4) return;
  int e0 = i * 4;
  int r = e0 / K;
  int c = e0 - r * K;
  const float4 v = *(const float4*)(s + e0);
  s16x4 p;
  p[0] = f2bf(v.x); p[1] = f2bf(v.y); p[2] = f2bf(v.z); p[3] = f2bf(v.w);
  short* dr = d + (size_t)r * (2 * K) + c;
  *(s16x4*)dr = p;
  *(s16x4*)(dr + K) = p;
}

__global__ void initx_k(const float* __restrict__ x, short* __restrict__ Xs, int n4) {
  int i = blockIdx.x * 256 + threadIdx.x;
  if (i >= n4) return;
  int e0 = i * 4;
  int r = e0 >> 8, c = e0 & 255;
  const float4 v = *(const float4*)(x + e0);
  s16x4 h, l;
  h[0] = f2bf(v.x); l[0] = f2bf(v.x - bf2f(h[0]));
  h[1] = f2bf(v.y); l[1] = f2bf(v.y - bf2f(h[1]));
  h[2] = f2bf(v.z); l[2] = f2bf(v.z - bf2f(h[2]));
  h[3] = f2bf(v.w); l[3] = f2bf(v.w - bf2f(h[3]));
  short* dr = Xs + ((size_t)r << 9) + c;
  *(s16x4*)dr = h;
  *(s16x4*)(dr + 256) = l;
}

__global__ void gather_k(const short* __restrict__ Xs, short* __restrict__ Xq) {
  int idx = blockIdx.x * 256 + threadIdx.x;  // < 12544*64
  int r = idx >> 6, ch = idx & 63;
  int bb = r / 49, p = r - bb * 49;
  int i = p / 7, j = p - i * 7;
  int sr = bb * 196 + i * 28 + j * 2;
  *(s16x8*)(Xq + ((size_t)r << 9) + (ch << 3)) =
      *(const s16x8*)(Xs + ((size_t)sr << 9) + (ch << 3));
}

extern "C" void kernel_launch(void* const* d_in, const int* in_sizes, int n_in,
                              void* d_out, int out_size, void* d_ws, size_t ws_size,
                              hipStream_t stream) {
  (void)in_sizes; (void)n_in; (void)out_size; (void)ws_size;
  const float* x = (const float*)d_in[0];
  const float* Wqkv = (const float*)d_in[1];
  const float* qkvs = (const float*)d_in[2];
  const float* qkvt = (const float*)d_in[3];
  const float* Wproj = (const float*)d_in[4];
  const float* projs = (const float*)d_in[5];
  const float* projt = (const float*)d_in[6];
  const float* abias = (const float*)d_in[7];
  const float* W1 = (const float*)d_in[8];
  const float* m1s = (const float*)d_in[9];
  const float* m1t = (const float*)d_in[10];
  const float* W2 = (const float*)d_in[11];
  const float* m2s = (const float*)d_in[12];
  const float* m2t = (const float*)d_in[13];
  const float* Wkv = (const float*)d_in[14];
  const float* kvs = (const float*)d_in[15];
  const float* kvt = (const float*)d_in[16];
  const float* Wq = (const float*)d_in[17];
  const float* qss = (const float*)d_in[18];
  const float* qst = (const float*)d_in[19];
  const float* Wp2 = (const float*)d_in[20];
  const float* p2s = (const float*)d_in[21];
  const float* p2t = (const float*)d_in[22];
  const float* sbias = (const float*)d_in[23];
  const float* Ws1 = (const float*)d_in[24];
  const float* s1s = (const float*)d_in[25];
  const float* s1t = (const float*)d_in[26];
  const float* Ws2 = (const float*)d_in[27];
  const float* s2s = (const float*)d_in[28];
  const float* s2t = (const float*)d_in[29];

  char* ws = (char*)d_ws;
  short* WB = (short*)ws;
  short* WDqkv = WB;
  short* WBproj = WB + 1048576;
  short* WD1 = WB + 1310720;
  short* WD2 = WB + 2359296;
  short* WDkv = WB + 3407872;
  short* WDq = WB + 4063232;
  short* WBp2 = WB + 4194304;
  short* WDs1 = WB + 4587520;
  short* WDs2 = WB + 5177344;

  short* Xs = (short*)(ws + 11534336);    // 50176 x 512 split (hi|lo)
  char* arena = ws + 62914560;
  short* QKVb = (short*)arena;            // 50176x512
  short* Ob = (short*)(arena + 51380224); // 50176x256
  short* Hs = (short*)arena;              // 50176x1024 split
  short* KVb = (short*)arena;             // 50176x1280
  short* Xqs = (short*)(arena + 128450560);  // 12544x512 split
  short* Qb = (short*)(arena + 141295616);   // 12544x256
  short* O2b = Xs;                        // 12544x1024 (Xs dead by then)
  short* X2s = (short*)(ws + 11534336 + 25690112);  // 12544x768 split
  short* H2s = (short*)arena;             // 12544x1536 split (KVb dead)

  auto cast = [&](const float* s, short* d, int n) {
    int n4 = n >> 2;
    cast_k<<<dim3((n4 + 255) / 256), dim3(256), 0, stream>>>(s, d, n4);
  };
  auto castdup = [&](const float* s, short* d, int rows, int K) {
    int n4 = (rows * K) >> 2;
    castdup_k<<<dim3((n4 + 255) / 256), dim3(256), 0, stream>>>(s, d, K, n4);
  };
  castdup(Wqkv, WDqkv, 2048, 256);
  cast(Wproj, WBproj, 262144);
  castdup(W1, WD1, 2048, 256);
  castdup(W2, WD2, 1024, 512);
  castdup(Wkv, WDkv, 1280, 256);
  castdup(Wq, WDq, 256, 256);
  cast(Wp2, WBp2, 393216);
  castdup(Ws1, WDs1, 768, 384);
  castdup(Ws2, WDs2, 384, 768);
  initx_k<<<12544, 256, 0, stream>>>(x, Xs, 3211264);

  for (int l = 0; l < 4; ++l) {
    gemm_k<0, 0, 0, 1, 0><<<392 * 4, 256, 0, stream>>>(
        Xs, WDqkv + l * 262144, qkvs + l * 512, qkvt + l * 512,
        nullptr, nullptr, QKVb, nullptr, 50176, 512, 512);
    attn_mfma_k<<<1024, 256, 0, stream>>>(QKVb, abias + l * 784, Ob);
    gemm_k<0, 1, 0, 0, 1><<<392 * 2, 256, 0, stream>>>(
        Ob, WBproj + l * 65536, projs + l * 256, projt + l * 256,
        Xs, nullptr, nullptr, Xs, 50176, 256, 256);
    gemm_k<1, 0, 0, 0, 1><<<392 * 4, 256, 0, stream>>>(
        Xs, WD1 + l * 262144, m1s + l * 512, m1t + l * 512,
        nullptr, nullptr, nullptr, Hs, 50176, 512, 512);
    gemm_k<0, 1, 0, 0, 1><<<392 * 2, 256, 0, stream>>>(
        Hs, WD2 + l * 262144, m2s + l * 256, m2t + l * 256,
        Xs, nullptr, nullptr, Xs, 50176, 256, 1024);
  }
  gemm_k<0, 0, 0, 1, 0><<<392 * 10, 256, 0, stream>>>(
      Xs, WDkv, kvs, kvt, nullptr, nullptr, KVb, nullptr, 50176, 1280, 512);
  gather_k<<<3136, 256, 0, stream>>>(Xs, Xqs);
  gemm_k<0, 0, 0, 1, 0><<<98 * 2, 256, 0, stream>>>(
      Xqs, WDq, qss, qst, nullptr, nullptr, Qb, nullptr, 12544, 256, 512);
  subattn_mfma_k<<<2048, 256, 0, stream>>>(KVb, Qb, sbias, O2b);
  gemm_k<0, 0, 0, 0, 1><<<98 * 3, 256, 0, stream>>>(
      O2b, WBp2, p2s, p2t, nullptr, nullptr, nullptr, X2s, 12544, 384, 1024);
  gemm_k<1, 0, 0, 0, 1><<<98 * 6, 256, 0, stream>>>(
      X2s, WDs1, s1s, s1t, nullptr, nullptr, nullptr, H2s, 12544, 768, 768);
  gemm_k<0, 1, 1, 0, 0><<<98 * 3, 256, 0, stream>>>(
      H2s, WDs2, s2s, s2t, X2s, (float*)d_out, nullptr, nullptr, 12544, 384, 1536);
}

// Round 5
// 964.502 us; speedup vs baseline: 3.1455x; 1.6727x over previous
//
#include <hip/hip_runtime.h>

typedef __attribute__((ext_vector_type(8))) short s16x8;
typedef __attribute__((ext_vector_type(4))) short s16x4;
typedef __attribute__((ext_vector_type(4))) float f32x4;
typedef __attribute__((ext_vector_type(8))) __fp16 f16x8;
typedef __attribute__((ext_vector_type(2))) __fp16 f16x2;

__device__ __forceinline__ short h16(float f) {
  __fp16 t = (__fp16)f;
  return *(short*)&t;
}
__device__ __forceinline__ unsigned pkh2(float a, float b) {
  f16x2 h = __builtin_amdgcn_cvt_pkrtz(a, b);
  return *(unsigned*)&h;
}
__device__ __forceinline__ float hswish(float v) { return v * fminf(fmaxf(v + 3.f, 0.f), 6.f) * (1.f / 6.f); }
__device__ __forceinline__ int iabs(int v) { return v < 0 ? -v : v; }

// ---------------- GEMM: out[M,N] = epi(A[M,K] @ W[N,K]^T), fp16 in, f32 acc ----------------
// 128x128 tile, 4 waves (2x2), 16x16x32 f16 MFMA, BK=64, reg-staged LDS with
// XOR swizzle (byte ^= (row&7)<<4) on write and read.
// RES: += f32 residual R (stride N). WF: write f32. WH: write fp16.
template <int ACT, int RES, int WF, int WH>
__global__ __launch_bounds__(256) void gemm_k(
    const short* __restrict__ A, const short* __restrict__ W,
    const float* __restrict__ sc, const float* __restrict__ tc,
    const float* __restrict__ R, float* __restrict__ oF, short* __restrict__ oH,
    int M, int N, int K) {
  __shared__ __align__(16) short As[128 * 64];
  __shared__ __align__(16) short Bs[128 * 64];
  const int tid = threadIdx.x;
  const int lane = tid & 63;
  const int wave = tid >> 6;
  const int wm = wave >> 1, wn = wave & 1;
  const int r15 = lane & 15, kq = lane >> 4;
  const int MT = M >> 7;
  const int mt = blockIdx.x % MT, nt = blockIdx.x / MT;
  const int m0 = mt << 7, n0 = nt << 7;

  f32x4 acc[4][4] = {};

  const int NT = K >> 6;
  s16x8 ra[4], rb[4];
#pragma unroll
  for (int i = 0; i < 4; ++i) {
    int c = i * 256 + tid;
    int row = c >> 3, col = (c & 7) << 3;
    ra[i] = *(const s16x8*)(A + (size_t)(m0 + row) * K + col);
    rb[i] = *(const s16x8*)(W + (size_t)(n0 + row) * K + col);
  }
  for (int kt = 0; kt < NT; ++kt) {
    __syncthreads();
#pragma unroll
    for (int i = 0; i < 4; ++i) {
      int c = i * 256 + tid;
      int byt = (c << 4) ^ (((c >> 3) & 7) << 4);
      *(s16x8*)((char*)As + byt) = ra[i];
      *(s16x8*)((char*)Bs + byt) = rb[i];
    }
    __syncthreads();
    if (kt + 1 < NT) {
      int k0 = (kt + 1) << 6;
#pragma unroll
      for (int i = 0; i < 4; ++i) {
        int c = i * 256 + tid;
        int row = c >> 3, col = (c & 7) << 3;
        ra[i] = *(const s16x8*)(A + (size_t)(m0 + row) * K + k0 + col);
        rb[i] = *(const s16x8*)(W + (size_t)(n0 + row) * K + k0 + col);
      }
    }
#pragma unroll
    for (int s = 0; s < 2; ++s) {
      f16x8 af[4], bq[4];
      const int cb = s * 64 + kq * 16;
#pragma unroll
      for (int f = 0; f < 4; ++f) {
        int rowA = wm * 64 + f * 16 + r15;
        int bytA = (rowA * 128 + cb) ^ ((rowA & 7) << 4);
        af[f] = *(const f16x8*)((const char*)As + bytA);
        int rowB = wn * 64 + f * 16 + r15;
        int bytB = (rowB * 128 + cb) ^ ((rowB & 7) << 4);
        bq[f] = *(const f16x8*)((const char*)Bs + bytB);
      }
#pragma unroll
      for (int fm = 0; fm < 4; ++fm)
#pragma unroll
        for (int fn = 0; fn < 4; ++fn)
          acc[fm][fn] = __builtin_amdgcn_mfma_f32_16x16x32_f16(af[fm], bq[fn], acc[fm][fn], 0, 0, 0);
    }
  }
#pragma unroll
  for (int fn = 0; fn < 4; ++fn) {
    const int cn = n0 + wn * 64 + fn * 16 + r15;
    const float scl = sc[cn], tcl = tc[cn];
#pragma unroll
    for (int fm = 0; fm < 4; ++fm) {
#pragma unroll
      for (int j = 0; j < 4; ++j) {
        const int rm = m0 + wm * 64 + fm * 16 + kq * 4 + j;
        float v = acc[fm][fn][j] * scl + tcl;
        if (ACT) v = hswish(v);
        size_t off = (size_t)rm * N + cn;
        if (RES) v += R[off];
        if (WF) oF[off] = v;
        if (WH) oH[off] = h16(v);
      }
    }
  }
}

// ---------------- MFMA attention (layer): S=196, d=32, v=64, H1=4, fp16 ----------------
// swapped QK^T: mfma(A=K, B=Q) -> lane owns k-chunk for q = lane&15.
// bias from precomputed global table BT[h][208][224] (k>=196 -> -30000).
__global__ __launch_bounds__(256) void attn_mfma_k(const short* __restrict__ QKV,
                                                   const float* __restrict__ BT,
                                                   short* __restrict__ O) {
  __shared__ __align__(16) short Vt[64 * 232];     // fp16 bits, [v][k], rows padded to 232
  __shared__ __align__(16) short P[4 * 16 * 232];  // fp16 bits, per wave [q][k]
  const int b = blockIdx.x >> 2, h = blockIdx.x & 3;
  const int tid = threadIdx.x;
  const int lane = tid & 63, wave = tid >> 6;
  const int l15 = lane & 15, g = lane >> 4, g4 = g * 4;
  const short* base = QKV + (size_t)b * (196 * 512);

  // zero pads: Vt cols [196,232), P cols [208,232)
  for (int c = tid; c < 1152; c += 256) {
    int v = c / 18, u = c - v * 18;
    *((unsigned*)Vt + v * 116 + 98 + u) = 0;
  }
  for (int c = tid; c < 768; c += 256) {
    int r = c / 12, u = c - r * 12;
    *((unsigned*)P + r * 116 + 104 + u) = 0;
  }
  // stage V transposed (fp16 bitwise): Vt[v][k] = V[k][v]
  for (int c = tid; c < 3136; c += 256) {
    int vp = c & 31, kp = c >> 5;
    const short* s = base + (size_t)(2 * kp) * 512 + h * 128 + 64 + 2 * vp;
    unsigned a0 = *(const unsigned*)s;
    unsigned a1 = *(const unsigned*)(s + 512);
    *((unsigned*)Vt + (2 * vp) * 116 + kp) = __builtin_amdgcn_perm(a1, a0, 0x05040100u);
    *((unsigned*)Vt + (2 * vp + 1) * 116 + kp) = __builtin_amdgcn_perm(a1, a0, 0x07060302u);
  }
  __syncthreads();

  // K fragments in registers (shared across this wave's q-tiles)
  f16x8 kf[13];
  {
    const short* kb = base + h * 128 + 32 + 8 * g;
#pragma unroll
    for (int t = 0; t < 13; ++t) {
      int kr = 16 * t + l15;
      if (kr > 195) kr = 195;
      kf[t] = *(const f16x8*)(kb + (size_t)kr * 512);
    }
  }

  for (int qt = wave; qt < 13; qt += 4) {
    int qr = 16 * qt + l15;
    if (qr > 195) qr = 195;
    f16x8 qf = *(const f16x8*)(base + (size_t)qr * 512 + h * 128 + 8 * g);
    f32x4 s[13];
#pragma unroll
    for (int t = 0; t < 13; ++t)
      s[t] = __builtin_amdgcn_mfma_f32_16x16x32_f16(kf[t], qf, f32x4{0.f, 0.f, 0.f, 0.f}, 0, 0, 0);

    const float* bt = BT + ((size_t)(h * 208 + 16 * qt + l15)) * 224 + 4 * g;
    float m = -1e30f;
#pragma unroll
    for (int t = 0; t < 13; ++t) {
      f32x4 bv = *(const f32x4*)(bt + 16 * t);
#pragma unroll
      for (int j = 0; j < 4; ++j) {
        float v = fmaf(s[t][j], 0.17677669529663687f, bv[j]);
        s[t][j] = v;
        m = fmaxf(m, v);
      }
    }
    m = fmaxf(m, __shfl_xor(m, 16));
    m = fmaxf(m, __shfl_xor(m, 32));
    float sum = 0.f;
#pragma unroll
    for (int t = 0; t < 13; ++t)
#pragma unroll
      for (int j = 0; j < 4; ++j) {
        float p = __expf(s[t][j] - m);
        s[t][j] = p;
        sum += p;
      }
    sum += __shfl_xor(sum, 16);
    sum += __shfl_xor(sum, 32);
    const float inv = 1.f / sum;
    unsigned* pw = (unsigned*)P + wave * (16 * 116) + l15 * 116;
#pragma unroll
    for (int t = 0; t < 13; ++t) {
      pw[8 * t + 2 * g] = pkh2(s[t][0] * inv, s[t][1] * inv);
      pw[8 * t + 2 * g + 1] = pkh2(s[t][2] * inv, s[t][3] * inv);
    }
    asm volatile("s_waitcnt lgkmcnt(0)" ::: "memory");

    f32x4 o[4] = {};
    const short* pr = P + wave * (16 * 232) + l15 * 232 + 8 * g;
    const short* vr = Vt + l15 * 232 + 8 * g;
#pragma unroll
    for (int kb = 0; kb < 7; ++kb) {
      f16x8 pa = *(const f16x8*)(pr + 32 * kb);
#pragma unroll
      for (int vt = 0; vt < 4; ++vt) {
        f16x8 vb = *(const f16x8*)(vr + vt * 16 * 232 + 32 * kb);
        o[vt] = __builtin_amdgcn_mfma_f32_16x16x32_f16(pa, vb, o[vt], 0, 0, 0);
      }
    }
#pragma unroll
    for (int vt = 0; vt < 4; ++vt)
#pragma unroll
      for (int j = 0; j < 4; ++j) {
        int qo = 16 * qt + g4 + j;
        if (qo < 196)
          O[(size_t)(b * 196 + qo) * 256 + h * 64 + vt * 16 + l15] = h16(hswish(o[vt][j]));
      }
  }
}

// -------- MFMA subsample attention: q 49(pad 64), k 196, d=32, v=128, H2=8, fp16 --------
__global__ __launch_bounds__(256) void subattn_mfma_k(const short* __restrict__ KVg,
                                                      const short* __restrict__ Qg,
                                                      const float* __restrict__ BT,
                                                      short* __restrict__ O2) {
  __shared__ __align__(16) short Vt[64 * 232];     // fp16, one 64-v chunk
  __shared__ __align__(16) short P[4 * 16 * 232];  // fp16
  const int b = blockIdx.x >> 3, h = blockIdx.x & 7;
  const int tid = threadIdx.x;
  const int lane = tid & 63, wave = tid >> 6;
  const int l15 = lane & 15, g = lane >> 4, g4 = g * 4;
  const short* base = KVg + (size_t)b * (196 * 1280) + h * 160;

  for (int c = tid; c < 1152; c += 256) {
    int v = c / 18, u = c - v * 18;
    *((unsigned*)Vt + v * 116 + 98 + u) = 0;
  }
  for (int c = tid; c < 768; c += 256) {
    int r = c / 12, u = c - r * 12;
    *((unsigned*)P + r * 116 + 104 + u) = 0;
  }

  // K frags in regs
  f16x8 kf[13];
#pragma unroll
  for (int t = 0; t < 13; ++t) {
    int kr = 16 * t + l15;
    if (kr > 195) kr = 195;
    kf[t] = *(const f16x8*)(base + (size_t)kr * 1280 + 8 * g);
  }

  f32x4 s[13];
  float inv;
  const int qt = wave;

  for (int half = 0; half < 2; ++half) {
    if (half) __syncthreads();  // all waves done with prev Vt chunk
    // stage Vt chunk (v in [64*half, 64*half+64))
    for (int c = tid; c < 3136; c += 256) {
      int vp = c & 31, kp = c >> 5;
      const short* sp = base + (size_t)(2 * kp) * 1280 + 32 + 64 * half + 2 * vp;
      unsigned a0 = *(const unsigned*)sp;
      unsigned a1 = *(const unsigned*)(sp + 1280);
      *((unsigned*)Vt + (2 * vp) * 116 + kp) = __builtin_amdgcn_perm(a1, a0, 0x05040100u);
      *((unsigned*)Vt + (2 * vp + 1) * 116 + kp) = __builtin_amdgcn_perm(a1, a0, 0x07060302u);
    }
    __syncthreads();

    if (half == 0) {
      int qr = 16 * qt + l15;  // q within padded 64
      int qc = qr > 48 ? 48 : qr;
      f16x8 qf = *(const f16x8*)(Qg + (size_t)(b * 49 + qc) * 256 + h * 32 + 8 * g);
#pragma unroll
      for (int t = 0; t < 13; ++t)
        s[t] = __builtin_amdgcn_mfma_f32_16x16x32_f16(kf[t], qf, f32x4{0.f, 0.f, 0.f, 0.f}, 0, 0, 0);
      const float* bt = BT + ((size_t)(h * 64 + qr)) * 224 + 4 * g;
      float m = -1e30f;
#pragma unroll
      for (int t = 0; t < 13; ++t) {
        f32x4 bv = *(const f32x4*)(bt + 16 * t);
#pragma unroll
        for (int j = 0; j < 4; ++j) {
          float v = fmaf(s[t][j], 0.17677669529663687f, bv[j]);
          s[t][j] = v;
          m = fmaxf(m, v);
        }
      }
      m = fmaxf(m, __shfl_xor(m, 16));
      m = fmaxf(m, __shfl_xor(m, 32));
      float sum = 0.f;
#pragma unroll
      for (int t = 0; t < 13; ++t)
#pragma unroll
        for (int j = 0; j < 4; ++j) {
          float p = __expf(s[t][j] - m);
          s[t][j] = p;
          sum += p;
        }
      sum += __shfl_xor(sum, 16);
      sum += __shfl_xor(sum, 32);
      inv = 1.f / sum;
      unsigned* pw = (unsigned*)P + wave * (16 * 116) + l15 * 116;
#pragma unroll
      for (int t = 0; t < 13; ++t) {
        pw[8 * t + 2 * g] = pkh2(s[t][0] * inv, s[t][1] * inv);
        pw[8 * t + 2 * g + 1] = pkh2(s[t][2] * inv, s[t][3] * inv);
      }
      asm volatile("s_waitcnt lgkmcnt(0)" ::: "memory");
    }

    f32x4 o[4] = {};
    const short* pr = P + wave * (16 * 232) + l15 * 232 + 8 * g;
    const short* vr = Vt + l15 * 232 + 8 * g;
#pragma unroll
    for (int kb = 0; kb < 7; ++kb) {
      f16x8 pa = *(const f16x8*)(pr + 32 * kb);
#pragma unroll
      for (int vt = 0; vt < 4; ++vt) {
        f16x8 vb = *(const f16x8*)(vr + vt * 16 * 232 + 32 * kb);
        o[vt] = __builtin_amdgcn_mfma_f32_16x16x32_f16(pa, vb, o[vt], 0, 0, 0);
      }
    }
#pragma unroll
    for (int vt = 0; vt < 4; ++vt)
#pragma unroll
      for (int j = 0; j < 4; ++j) {
        int qo = 16 * qt + g4 + j;
        if (qo < 49)
          O2[(size_t)(b * 49 + qo) * 1024 + h * 128 + half * 64 + vt * 16 + l15] =
              h16(hswish(o[vt][j]));
      }
  }
}

// ---------------- utility kernels ----------------
__global__ void cast_h(const float* __restrict__ s, short* __restrict__ d, int n4) {
  int i = blockIdx.x * 256 + threadIdx.x;
  if (i >= n4) return;
  const float4 v = ((const float4*)s)[i];
  s16x4 r;
  r[0] = h16(v.x); r[1] = h16(v.y); r[2] = h16(v.z); r[3] = h16(v.w);
  ((s16x4*)d)[i] = r;
}

// bias table 1: [l][h][208][224] f32; k>=196 -> -30000
__global__ void btab1_k(const float* __restrict__ ab, float* __restrict__ T) {
  int i = blockIdx.x * 256 + threadIdx.x;
  if (i >= 745472) return;
  int k = i % 224;
  int rest = i / 224;
  int q = rest % 208;
  int lh = rest / 208;  // l*4+h
  float v = -30000.f;
  if (k < 196) {
    int qc = q < 196 ? q : 195;
    int qi = qc / 14, qj = qc - 14 * qi, ki = k / 14, kj = k - 14 * ki;
    v = ab[lh * 196 + iabs(qi - ki) * 14 + iabs(qj - kj)];
  }
  T[i] = v;
}

// bias table 2: [h][64][224] f32
__global__ void btab2_k(const float* __restrict__ sb, float* __restrict__ T) {
  int i = blockIdx.x * 256 + threadIdx.x;
  if (i >= 114688) return;
  int k = i % 224;
  int rest = i / 224;
  int q = rest % 64;
  int h = rest / 64;
  float v = -30000.f;
  if (k < 196) {
    int qc = q < 49 ? q : 48;
    int qi = qc / 7, qj = qc - 7 * qi, ki = k / 14, kj = k - 14 * ki;
    v = sb[h * 196 + iabs(2 * qi - ki) * 14 + iabs(2 * qj - kj)];
  }
  T[i] = v;
}

// x f32 -> X f32 copy + Xh fp16
__global__ void initx_k(const float* __restrict__ x, float* __restrict__ X,
                        short* __restrict__ Xh, int n4) {
  int i = blockIdx.x * 256 + threadIdx.x;
  if (i >= n4) return;
  const float4 v = ((const float4*)x)[i];
  ((float4*)X)[i] = v;
  s16x4 r;
  r[0] = h16(v.x); r[1] = h16(v.y); r[2] = h16(v.z); r[3] = h16(v.w);
  ((s16x4*)Xh)[i] = r;
}

// gather strided 7x7 rows out of 14x14 (256 fp16 per row, 32 16B-chunks)
__global__ void gather_k(const short* __restrict__ Xh, short* __restrict__ Xq) {
  int idx = blockIdx.x * 256 + threadIdx.x;  // < 12544*32
  int r = idx >> 5, ch = idx & 31;
  int bb = r / 49, p = r - bb * 49;
  int i = p / 7, j = p - i * 7;
  int sr = bb * 196 + i * 28 + j * 2;
  *(s16x8*)(Xq + ((size_t)r << 8) + (ch << 3)) =
      *(const s16x8*)(Xh + ((size_t)sr << 8) + (ch << 3));
}

extern "C" void kernel_launch(void* const* d_in, const int* in_sizes, int n_in,
                              void* d_out, int out_size, void* d_ws, size_t ws_size,
                              hipStream_t stream) {
  (void)in_sizes; (void)n_in; (void)out_size; (void)ws_size;
  const float* x = (const float*)d_in[0];
  const float* Wqkv = (const float*)d_in[1];
  const float* qkvs = (const float*)d_in[2];
  const float* qkvt = (const float*)d_in[3];
  const float* Wproj = (const float*)d_in[4];
  const float* projs = (const float*)d_in[5];
  const float* projt = (const float*)d_in[6];
  const float* abias = (const float*)d_in[7];
  const float* W1 = (const float*)d_in[8];
  const float* m1s = (const float*)d_in[9];
  const float* m1t = (const float*)d_in[10];
  const float* W2 = (const float*)d_in[11];
  const float* m2s = (const float*)d_in[12];
  const float* m2t = (const float*)d_in[13];
  const float* Wkv = (const float*)d_in[14];
  const float* kvs = (const float*)d_in[15];
  const float* kvt = (const float*)d_in[16];
  const float* Wq = (const float*)d_in[17];
  const float* qss = (const float*)d_in[18];
  const float* qst = (const float*)d_in[19];
  const float* Wp2 = (const float*)d_in[20];
  const float* p2s = (const float*)d_in[21];
  const float* p2t = (const float*)d_in[22];
  const float* sbias = (const float*)d_in[23];
  const float* Ws1 = (const float*)d_in[24];
  const float* s1s = (const float*)d_in[25];
  const float* s1t = (const float*)d_in[26];
  const float* Ws2 = (const float*)d_in[27];
  const float* s2s = (const float*)d_in[28];
  const float* s2t = (const float*)d_in[29];

  char* ws = (char*)d_ws;
  // fp16 weight arena (element offsets into WH)
  short* WH = (short*)ws;
  short* WHqkv = WH;                 // 4x512x256
  short* WHproj = WH + 524288;       // 4x256x256
  short* WH1 = WH + 786432;          // 4x512x256
  short* WH2 = WH + 1310720;         // 4x256x512
  short* WHkv = WH + 1835008;        // 1280x256
  short* WHq = WH + 2162688;         // 256x256
  short* WHp2 = WH + 2228224;        // 384x1024
  short* WHs1 = WH + 2621440;        // 768x384
  short* WHs2 = WH + 2916352;        // 384x768  (end: 3211264 el = 6422528 B)

  float* T1 = (float*)(ws + 6422528);   // [4][4][208][224] f32 = 2981888 B
  float* T2 = (float*)(ws + 9404416);   // [8][64][224] f32 = 458752 B
  short* Xh = (short*)(ws + 9863168);   // 50176x256 fp16 (25690112 B)
  float* X = (float*)(ws + 35553280);   // 50176x256 f32 (51380224 B)
  short* QKVh = (short*)(ws + 86933504);  // 50176x512 fp16 (51380224 B); also H
  short* Hh = QKVh;
  short* Oh = (short*)(ws + 138313728);   // 50176x256 fp16 (25690112 B)
  short* KVh = (short*)(ws + 35553280);   // 50176x1280 fp16 (128450560 B), aliases X (dead)
  short* Xqh = (short*)(ws + 164003840);  // 12544x256 fp16 (6422528 B)
  short* Qh = (short*)(ws + 170426368);   // 12544x256 fp16 (6422528 B)  [peak: 176848896]
  short* O2h = (short*)(ws + 9863168);    // 12544x1024 fp16 (25690112 B), aliases Xh (dead)
  float* X2 = (float*)(ws + 35553280);    // 12544x384 f32 (19267584 B), aliases KV head (dead)
  short* X2h = (short*)(ws + 54820864);   // 12544x384 fp16 (9633792 B)
  short* H2h = (short*)(ws + 64454656);   // 12544x768 fp16 (19267584 B)

  auto cast = [&](const float* s, short* d, int n) {
    int n4 = n >> 2;
    cast_h<<<dim3((n4 + 255) / 256), dim3(256), 0, stream>>>(s, d, n4);
  };
  cast(Wqkv, WHqkv, 524288);
  cast(Wproj, WHproj, 262144);
  cast(W1, WH1, 524288);
  cast(W2, WH2, 524288);
  cast(Wkv, WHkv, 327680);
  cast(Wq, WHq, 65536);
  cast(Wp2, WHp2, 393216);
  cast(Ws1, WHs1, 294912);
  cast(Ws2, WHs2, 294912);
  btab1_k<<<2912, 256, 0, stream>>>(abias, T1);
  btab2_k<<<448, 256, 0, stream>>>(sbias, T2);
  initx_k<<<12544, 256, 0, stream>>>(x, X, Xh, 3211264);

  for (int l = 0; l < 4; ++l) {
    gemm_k<0, 0, 0, 1><<<392 * 4, 256, 0, stream>>>(
        Xh, WHqkv + l * 131072, qkvs + l * 512, qkvt + l * 512,
        nullptr, nullptr, QKVh, 50176, 512, 256);
    attn_mfma_k<<<1024, 256, 0, stream>>>(QKVh, T1 + l * 186368, Oh);
    gemm_k<0, 1, 1, 1><<<392 * 2, 256, 0, stream>>>(
        Oh, WHproj + l * 65536, projs + l * 256, projt + l * 256,
        X, X, Xh, 50176, 256, 256);
    gemm_k<1, 0, 0, 1><<<392 * 4, 256, 0, stream>>>(
        Xh, WH1 + l * 131072, m1s + l * 512, m1t + l * 512,
        nullptr, nullptr, Hh, 50176, 512, 256);
    gemm_k<0, 1, 1, 1><<<392 * 2, 256, 0, stream>>>(
        Hh, WH2 + l * 131072, m2s + l * 256, m2t + l * 256,
        X, X, Xh, 50176, 256, 512);
  }
  gemm_k<0, 0, 0, 1><<<392 * 10, 256, 0, stream>>>(
      Xh, WHkv, kvs, kvt, nullptr, nullptr, KVh, 50176, 1280, 256);
  gather_k<<<1568, 256, 0, stream>>>(Xh, Xqh);
  gemm_k<0, 0, 0, 1><<<98 * 2, 256, 0, stream>>>(
      Xqh, WHq, qss, qst, nullptr, nullptr, Qh, 12544, 256, 256);
  subattn_mfma_k<<<2048, 256, 0, stream>>>(KVh, Qh, T2, O2h);
  gemm_k<0, 0, 1, 1><<<98 * 3, 256, 0, stream>>>(
      O2h, WHp2, p2s, p2t, nullptr, X2, X2h, 12544, 384, 1024);
  gemm_k<1, 0, 0, 1><<<98 * 6, 256, 0, stream>>>(
      X2h, WHs1, s1s, s1t, nullptr, nullptr, H2h, 12544, 768, 384);
  gemm_k<0, 1, 1, 0><<<98 * 3, 256, 0, stream>>>(
      H2h, WHs2, s2s, s2t, X2, (float*)d_out, nullptr, 12544, 384, 768);
}

// Round 7
// 952.838 us; speedup vs baseline: 3.1840x; 1.0122x over previous
//
#include <hip/hip_runtime.h>

typedef __attribute__((ext_vector_type(8))) short s16x8;
typedef __attribute__((ext_vector_type(4))) short s16x4;
typedef __attribute__((ext_vector_type(4))) float f32x4;
typedef __attribute__((ext_vector_type(8))) __fp16 f16x8;
typedef __attribute__((ext_vector_type(2))) __fp16 f16x2;

#define AS1 __attribute__((address_space(1)))
#define AS3 __attribute__((address_space(3)))

__device__ __forceinline__ short h16(float f) {
  __fp16 t = (__fp16)f;
  return *(short*)&t;
}
__device__ __forceinline__ unsigned pkh2(float a, float b) {
  f16x2 h = __builtin_amdgcn_cvt_pkrtz(a, b);
  return *(unsigned*)&h;
}
__device__ __forceinline__ float hswish(float v) { return v * fminf(fmaxf(v + 3.f, 0.f), 6.f) * (1.f / 6.f); }
__device__ __forceinline__ int iabs(int v) { return v < 0 ? -v : v; }

// ---------------- GEMM: out[M,N] = epi(A[M,K] @ W[N,K]^T), fp16 in, f32 acc ----------------
// 128x128 tile, 4 waves (2x2), 16x16x32 f16 MFMA, BK=64.
// global_load_lds (builtin) staging: LDS dest linear, global source col
// pre-swizzled so XOR-swizzled frag reads (byte ^= (row&7)<<4) see right data.
template <int ACT, int RES, int WF, int WH>
__global__ __launch_bounds__(256) void gemm_k(
    const short* __restrict__ A, const short* __restrict__ W,
    const float* __restrict__ sc, const float* __restrict__ tc,
    const float* __restrict__ R, float* __restrict__ oF, short* __restrict__ oH,
    int M, int N, int K) {
  __shared__ __align__(16) short As[128 * 64];
  __shared__ __align__(16) short Bs[128 * 64];
  const int tid = threadIdx.x;
  const int lane = tid & 63;
  const int wave = tid >> 6;
  const int wm = wave >> 1, wn = wave & 1;
  const int r15 = lane & 15, kq = lane >> 4;
  const int MT = M >> 7;
  const int mt = blockIdx.x % MT, nt = blockIdx.x / MT;
  const int m0 = mt << 7, n0 = nt << 7;

  // slot c = i*256+tid holds row (32i + tid>>3), global chunk (tid&7)^((tid>>3)&7)
  const int tr = tid >> 3;
  const int col8 = (tid & 7) ^ (tr & 7);
  const short* pa = A + (size_t)(m0 + tr) * K + 8 * col8;
  const short* pb = W + (size_t)(n0 + tr) * K + 8 * col8;
  short* la = As + tid * 8;
  short* lb = Bs + tid * 8;

  f32x4 acc[4][4] = {};
  const int NT = K >> 6;

#define ISSUE(kt)                                                                     \
  {                                                                                   \
    _Pragma("unroll") for (int i = 0; i < 4; ++i) {                                   \
      __builtin_amdgcn_global_load_lds(                                               \
          (const AS1 void*)(pa + (size_t)(32 * i) * K + (kt) * 64),                   \
          (AS3 void*)(la + i * 2048), 16, 0, 0);                                      \
      __builtin_amdgcn_global_load_lds(                                               \
          (const AS1 void*)(pb + (size_t)(32 * i) * K + (kt) * 64),                   \
          (AS3 void*)(lb + i * 2048), 16, 0, 0);                                      \
    }                                                                                 \
  }

  ISSUE(0)
  for (int kt = 0; kt < NT; ++kt) {
    __syncthreads();  // compiler drains vmcnt(0): DMA for kt landed
    f16x8 af[2][4], bq[2][4];
#pragma unroll
    for (int s = 0; s < 2; ++s) {
      const int cb = s * 64 + kq * 16;
#pragma unroll
      for (int f = 0; f < 4; ++f) {
        int rowA = wm * 64 + f * 16 + r15;
        af[s][f] = *(const f16x8*)((const char*)As + ((rowA * 128 + cb) ^ ((rowA & 7) << 4)));
        int rowB = wn * 64 + f * 16 + r15;
        bq[s][f] = *(const f16x8*)((const char*)Bs + ((rowB * 128 + cb) ^ ((rowB & 7) << 4)));
      }
    }
    __syncthreads();  // lgkmcnt(0) drained: all waves' frag reads done
    if (kt + 1 < NT) ISSUE(kt + 1)
    __builtin_amdgcn_sched_barrier(0);  // keep MFMAs below the load issue
#pragma unroll
    for (int s = 0; s < 2; ++s)
#pragma unroll
      for (int fm = 0; fm < 4; ++fm)
#pragma unroll
        for (int fn = 0; fn < 4; ++fn)
          acc[fm][fn] = __builtin_amdgcn_mfma_f32_16x16x32_f16(af[s][fm], bq[s][fn], acc[fm][fn], 0, 0, 0);
  }
#undef ISSUE

#pragma unroll
  for (int fn = 0; fn < 4; ++fn) {
    const int cn = n0 + wn * 64 + fn * 16 + r15;
    const float scl = sc[cn], tcl = tc[cn];
#pragma unroll
    for (int fm = 0; fm < 4; ++fm) {
#pragma unroll
      for (int j = 0; j < 4; ++j) {
        const int rm = m0 + wm * 64 + fm * 16 + kq * 4 + j;
        float v = acc[fm][fn][j] * scl + tcl;
        if (ACT) v = hswish(v);
        size_t off = (size_t)rm * N + cn;
        if (RES) v += R[off];
        if (WF) oF[off] = v;
        if (WH) oH[off] = h16(v);
      }
    }
  }
}

// ---------------- MFMA attention (layer): S=196, d=32, v=64, H1=4, fp16 ----------------
__global__ __launch_bounds__(256) void attn_mfma_k(const short* __restrict__ QKV,
                                                   const float* __restrict__ BT,
                                                   short* __restrict__ O) {
  __shared__ __align__(16) short Vt[64 * 232];     // fp16 bits, [v][k], rows padded to 232
  __shared__ __align__(16) short P[4 * 16 * 232];  // fp16 bits, per wave [q][k]
  const int b = blockIdx.x >> 2, h = blockIdx.x & 3;
  const int tid = threadIdx.x;
  const int lane = tid & 63, wave = tid >> 6;
  const int l15 = lane & 15, g = lane >> 4, g4 = g * 4;
  const short* base = QKV + (size_t)b * (196 * 512);

  // zero pads: Vt cols [196,232), P cols [208,232)
  for (int c = tid; c < 1152; c += 256) {
    int v = c / 18, u = c - v * 18;
    *((unsigned*)Vt + v * 116 + 98 + u) = 0;
  }
  for (int c = tid; c < 768; c += 256) {
    int r = c / 12, u = c - r * 12;
    *((unsigned*)P + r * 116 + 104 + u) = 0;
  }
  // stage V transposed; lane map (vp8 fast over cols) keeps LDS writes ~2-way
  for (int c = tid; c < 3136; c += 256) {
    int vp8 = c & 7, rest = c >> 3;
    int vg = rest / 98, kp = rest - vg * 98;
    int vp = vg * 8 + vp8;
    const short* s = base + (size_t)(2 * kp) * 512 + h * 128 + 64 + 2 * vp;
    unsigned a0 = *(const unsigned*)s;
    unsigned a1 = *(const unsigned*)(s + 512);
    *((unsigned*)Vt + (2 * vp) * 116 + kp) = __builtin_amdgcn_perm(a1, a0, 0x05040100u);
    *((unsigned*)Vt + (2 * vp + 1) * 116 + kp) = __builtin_amdgcn_perm(a1, a0, 0x07060302u);
  }
  __syncthreads();

  // K fragments in registers (shared across this wave's q-tiles)
  f16x8 kf[13];
  {
    const short* kb = base + h * 128 + 32 + 8 * g;
#pragma unroll
    for (int t = 0; t < 13; ++t) {
      int kr = 16 * t + l15;
      if (kr > 195) kr = 195;
      kf[t] = *(const f16x8*)(kb + (size_t)kr * 512);
    }
  }

  for (int qt = wave; qt < 13; qt += 4) {
    int qr = 16 * qt + l15;
    if (qr > 195) qr = 195;
    f16x8 qf = *(const f16x8*)(base + (size_t)qr * 512 + h * 128 + 8 * g);
    f32x4 s[13];
    __builtin_amdgcn_s_setprio(1);
#pragma unroll
    for (int t = 0; t < 13; ++t)
      s[t] = __builtin_amdgcn_mfma_f32_16x16x32_f16(kf[t], qf, f32x4{0.f, 0.f, 0.f, 0.f}, 0, 0, 0);
    __builtin_amdgcn_s_setprio(0);

    const float* bt = BT + ((size_t)(h * 208 + 16 * qt + l15)) * 224 + 4 * g;
    float m = -1e30f;
#pragma unroll
    for (int t = 0; t < 13; ++t) {
      f32x4 bv = *(const f32x4*)(bt + 16 * t);
#pragma unroll
      for (int j = 0; j < 4; ++j) {
        float v = fmaf(s[t][j], 0.17677669529663687f, bv[j]);
        s[t][j] = v;
        m = fmaxf(m, v);
      }
    }
    m = fmaxf(m, __shfl_xor(m, 16));
    m = fmaxf(m, __shfl_xor(m, 32));
    float sum = 0.f;
#pragma unroll
    for (int t = 0; t < 13; ++t)
#pragma unroll
      for (int j = 0; j < 4; ++j) {
        float p = __expf(s[t][j] - m);
        s[t][j] = p;
        sum += p;
      }
    sum += __shfl_xor(sum, 16);
    sum += __shfl_xor(sum, 32);
    const float inv = 1.f / sum;
    unsigned* pw = (unsigned*)P + wave * (16 * 116) + l15 * 116;
#pragma unroll
    for (int t = 0; t < 13; ++t) {
      pw[8 * t + 2 * g] = pkh2(s[t][0] * inv, s[t][1] * inv);
      pw[8 * t + 2 * g + 1] = pkh2(s[t][2] * inv, s[t][3] * inv);
    }
    asm volatile("s_waitcnt lgkmcnt(0)" ::: "memory");
    __builtin_amdgcn_sched_barrier(0);

    f32x4 o[4] = {};
    const short* pr = P + wave * (16 * 232) + l15 * 232 + 8 * g;
    const short* vr = Vt + l15 * 232 + 8 * g;
    __builtin_amdgcn_s_setprio(1);
#pragma unroll
    for (int kb = 0; kb < 7; ++kb) {
      f16x8 pa = *(const f16x8*)(pr + 32 * kb);
#pragma unroll
      for (int vt = 0; vt < 4; ++vt) {
        f16x8 vb = *(const f16x8*)(vr + vt * 16 * 232 + 32 * kb);
        o[vt] = __builtin_amdgcn_mfma_f32_16x16x32_f16(pa, vb, o[vt], 0, 0, 0);
      }
    }
    __builtin_amdgcn_s_setprio(0);
#pragma unroll
    for (int vt = 0; vt < 4; ++vt)
#pragma unroll
      for (int j = 0; j < 4; ++j) {
        int qo = 16 * qt + g4 + j;
        if (qo < 196)
          O[(size_t)(b * 196 + qo) * 256 + h * 64 + vt * 16 + l15] = h16(hswish(o[vt][j]));
      }
  }
}

// -------- MFMA subsample attention: q 49(pad 64), k 196, d=32, v=128, H2=8, fp16 --------
__global__ __launch_bounds__(256) void subattn_mfma_k(const short* __restrict__ KVg,
                                                      const short* __restrict__ Qg,
                                                      const float* __restrict__ BT,
                                                      short* __restrict__ O2) {
  __shared__ __align__(16) short Vt[64 * 232];     // fp16, one 64-v chunk
  __shared__ __align__(16) short P[4 * 16 * 232];  // fp16
  const int b = blockIdx.x >> 3, h = blockIdx.x & 7;
  const int tid = threadIdx.x;
  const int lane = tid & 63, wave = tid >> 6;
  const int l15 = lane & 15, g = lane >> 4, g4 = g * 4;
  const short* base = KVg + (size_t)b * (196 * 1280) + h * 160;

  for (int c = tid; c < 1152; c += 256) {
    int v = c / 18, u = c - v * 18;
    *((unsigned*)Vt + v * 116 + 98 + u) = 0;
  }
  for (int c = tid; c < 768; c += 256) {
    int r = c / 12, u = c - r * 12;
    *((unsigned*)P + r * 116 + 104 + u) = 0;
  }

  // K frags in regs
  f16x8 kf[13];
#pragma unroll
  for (int t = 0; t < 13; ++t) {
    int kr = 16 * t + l15;
    if (kr > 195) kr = 195;
    kf[t] = *(const f16x8*)(base + (size_t)kr * 1280 + 8 * g);
  }

  f32x4 s[13];
  float inv;
  const int qt = wave;

  for (int half = 0; half < 2; ++half) {
    if (half) __syncthreads();  // all waves done with prev Vt chunk
    for (int c = tid; c < 3136; c += 256) {
      int vp8 = c & 7, rest = c >> 3;
      int vg = rest / 98, kp = rest - vg * 98;
      int vp = vg * 8 + vp8;
      const short* sp = base + (size_t)(2 * kp) * 1280 + 32 + 64 * half + 2 * vp;
      unsigned a0 = *(const unsigned*)sp;
      unsigned a1 = *(const unsigned*)(sp + 1280);
      *((unsigned*)Vt + (2 * vp) * 116 + kp) = __builtin_amdgcn_perm(a1, a0, 0x05040100u);
      *((unsigned*)Vt + (2 * vp + 1) * 116 + kp) = __builtin_amdgcn_perm(a1, a0, 0x07060302u);
    }
    __syncthreads();

    if (half == 0) {
      int qr = 16 * qt + l15;
      int qc = qr > 48 ? 48 : qr;
      f16x8 qf = *(const f16x8*)(Qg + (size_t)(b * 49 + qc) * 256 + h * 32 + 8 * g);
      __builtin_amdgcn_s_setprio(1);
#pragma unroll
      for (int t = 0; t < 13; ++t)
        s[t] = __builtin_amdgcn_mfma_f32_16x16x32_f16(kf[t], qf, f32x4{0.f, 0.f, 0.f, 0.f}, 0, 0, 0);
      __builtin_amdgcn_s_setprio(0);
      const float* bt = BT + ((size_t)(h * 64 + qr)) * 224 + 4 * g;
      float m = -1e30f;
#pragma unroll
      for (int t = 0; t < 13; ++t) {
        f32x4 bv = *(const f32x4*)(bt + 16 * t);
#pragma unroll
        for (int j = 0; j < 4; ++j) {
          float v = fmaf(s[t][j], 0.17677669529663687f, bv[j]);
          s[t][j] = v;
          m = fmaxf(m, v);
        }
      }
      m = fmaxf(m, __shfl_xor(m, 16));
      m = fmaxf(m, __shfl_xor(m, 32));
      float sum = 0.f;
#pragma unroll
      for (int t = 0; t < 13; ++t)
#pragma unroll
        for (int j = 0; j < 4; ++j) {
          float p = __expf(s[t][j] - m);
          s[t][j] = p;
          sum += p;
        }
      sum += __shfl_xor(sum, 16);
      sum += __shfl_xor(sum, 32);
      inv = 1.f / sum;
      unsigned* pw = (unsigned*)P + wave * (16 * 116) + l15 * 116;
#pragma unroll
      for (int t = 0; t < 13; ++t) {
        pw[8 * t + 2 * g] = pkh2(s[t][0] * inv, s[t][1] * inv);
        pw[8 * t + 2 * g + 1] = pkh2(s[t][2] * inv, s[t][3] * inv);
      }
      asm volatile("s_waitcnt lgkmcnt(0)" ::: "memory");
      __builtin_amdgcn_sched_barrier(0);
    }

    f32x4 o[4] = {};
    const short* pr = P + wave * (16 * 232) + l15 * 232 + 8 * g;
    const short* vr = Vt + l15 * 232 + 8 * g;
    __builtin_amdgcn_s_setprio(1);
#pragma unroll
    for (int kb = 0; kb < 7; ++kb) {
      f16x8 pa = *(const f16x8*)(pr + 32 * kb);
#pragma unroll
      for (int vt = 0; vt < 4; ++vt) {
        f16x8 vb = *(const f16x8*)(vr + vt * 16 * 232 + 32 * kb);
        o[vt] = __builtin_amdgcn_mfma_f32_16x16x32_f16(pa, vb, o[vt], 0, 0, 0);
      }
    }
    __builtin_amdgcn_s_setprio(0);
#pragma unroll
    for (int vt = 0; vt < 4; ++vt)
#pragma unroll
      for (int j = 0; j < 4; ++j) {
        int qo = 16 * qt + g4 + j;
        if (qo < 49)
          O2[(size_t)(b * 49 + qo) * 1024 + h * 128 + half * 64 + vt * 16 + l15] =
              h16(hswish(o[vt][j]));
      }
  }
}

// ---------------- utility kernels ----------------
__global__ void cast_h(const float* __restrict__ s, short* __restrict__ d, int n4) {
  int i = blockIdx.x * 256 + threadIdx.x;
  if (i >= n4) return;
  const float4 v = ((const float4*)s)[i];
  s16x4 r;
  r[0] = h16(v.x); r[1] = h16(v.y); r[2] = h16(v.z); r[3] = h16(v.w);
  ((s16x4*)d)[i] = r;
}

// bias table 1: [l][h][208][224] f32; k>=196 -> -30000
__global__ void btab1_k(const float* __restrict__ ab, float* __restrict__ T) {
  int i = blockIdx.x * 256 + threadIdx.x;
  if (i >= 745472) return;
  int k = i % 224;
  int rest = i / 224;
  int q = rest % 208;
  int lh = rest / 208;
  float v = -30000.f;
  if (k < 196) {
    int qc = q < 196 ? q : 195;
    int qi = qc / 14, qj = qc - 14 * qi, ki = k / 14, kj = k - 14 * ki;
    v = ab[lh * 196 + iabs(qi - ki) * 14 + iabs(qj - kj)];
  }
  T[i] = v;
}

// bias table 2: [h][64][224] f32
__global__ void btab2_k(const float* __restrict__ sb, float* __restrict__ T) {
  int i = blockIdx.x * 256 + threadIdx.x;
  if (i >= 114688) return;
  int k = i % 224;
  int rest = i / 224;
  int q = rest % 64;
  int h = rest / 64;
  float v = -30000.f;
  if (k < 196) {
    int qc = q < 49 ? q : 48;
    int qi = qc / 7, qj = qc - 7 * qi, ki = k / 14, kj = k - 14 * ki;
    v = sb[h * 196 + iabs(2 * qi - ki) * 14 + iabs(2 * qj - kj)];
  }
  T[i] = v;
}

// gather strided 7x7 rows out of 14x14 (256 fp16 per row, 32 16B-chunks)
__global__ void gather_k(const short* __restrict__ Xh, short* __restrict__ Xq) {
  int idx = blockIdx.x * 256 + threadIdx.x;  // < 12544*32
  int r = idx >> 5, ch = idx & 31;
  int bb = r / 49, p = r - bb * 49;
  int i = p / 7, j = p - i * 7;
  int sr = bb * 196 + i * 28 + j * 2;
  *(s16x8*)(Xq + ((size_t)r << 8) + (ch << 3)) =
      *(const s16x8*)(Xh + ((size_t)sr << 8) + (ch << 3));
}

extern "C" void kernel_launch(void* const* d_in, const int* in_sizes, int n_in,
                              void* d_out, int out_size, void* d_ws, size_t ws_size,
                              hipStream_t stream) {
  (void)in_sizes; (void)n_in; (void)out_size; (void)ws_size;
  const float* x = (const float*)d_in[0];
  const float* Wqkv = (const float*)d_in[1];
  const float* qkvs = (const float*)d_in[2];
  const float* qkvt = (const float*)d_in[3];
  const float* Wproj = (const float*)d_in[4];
  const float* projs = (const float*)d_in[5];
  const float* projt = (const float*)d_in[6];
  const float* abias = (const float*)d_in[7];
  const float* W1 = (const float*)d_in[8];
  const float* m1s = (const float*)d_in[9];
  const float* m1t = (const float*)d_in[10];
  const float* W2 = (const float*)d_in[11];
  const float* m2s = (const float*)d_in[12];
  const float* m2t = (const float*)d_in[13];
  const float* Wkv = (const float*)d_in[14];
  const float* kvs = (const float*)d_in[15];
  const float* kvt = (const float*)d_in[16];
  const float* Wq = (const float*)d_in[17];
  const float* qss = (const float*)d_in[18];
  const float* qst = (const float*)d_in[19];
  const float* Wp2 = (const float*)d_in[20];
  const float* p2s = (const float*)d_in[21];
  const float* p2t = (const float*)d_in[22];
  const float* sbias = (const float*)d_in[23];
  const float* Ws1 = (const float*)d_in[24];
  const float* s1s = (const float*)d_in[25];
  const float* s1t = (const float*)d_in[26];
  const float* Ws2 = (const float*)d_in[27];
  const float* s2s = (const float*)d_in[28];
  const float* s2t = (const float*)d_in[29];

  char* ws = (char*)d_ws;
  short* WH = (short*)ws;
  short* WHqkv = WH;                 // 4x512x256
  short* WHproj = WH + 524288;       // 4x256x256
  short* WH1 = WH + 786432;          // 4x512x256
  short* WH2 = WH + 1310720;         // 4x256x512
  short* WHkv = WH + 1835008;        // 1280x256
  short* WHq = WH + 2162688;         // 256x256
  short* WHp2 = WH + 2228224;        // 384x1024
  short* WHs1 = WH + 2621440;        // 768x384
  short* WHs2 = WH + 2916352;        // 384x768

  float* T1 = (float*)(ws + 6422528);   // [4][4][208][224] f32
  float* T2 = (float*)(ws + 9404416);   // [8][64][224] f32
  short* Xh = (short*)(ws + 9863168);   // 50176x256 fp16
  float* X = (float*)(ws + 35553280);   // 50176x256 f32
  short* QKVh = (short*)(ws + 86933504);  // 50176x512 fp16; also H
  short* Hh = QKVh;
  short* Oh = (short*)(ws + 138313728);   // 50176x256 fp16
  short* KVh = (short*)(ws + 35553280);   // 50176x1280 fp16, aliases X (dead)
  short* Xqh = (short*)(ws + 164003840);  // 12544x256 fp16
  short* Qh = (short*)(ws + 170426368);   // 12544x256 fp16
  short* O2h = (short*)(ws + 9863168);    // 12544x1024 fp16, aliases Xh (dead)
  float* X2 = (float*)(ws + 35553280);    // 12544x384 f32, aliases KV head (dead)
  short* X2h = (short*)(ws + 54820864);   // 12544x384 fp16
  short* H2h = (short*)(ws + 64454656);   // 12544x768 fp16

  auto cast = [&](const float* s, short* d, int n) {
    int n4 = n >> 2;
    cast_h<<<dim3((n4 + 255) / 256), dim3(256), 0, stream>>>(s, d, n4);
  };
  cast(Wqkv, WHqkv, 524288);
  cast(Wproj, WHproj, 262144);
  cast(W1, WH1, 524288);
  cast(W2, WH2, 524288);
  cast(Wkv, WHkv, 327680);
  cast(Wq, WHq, 65536);
  cast(Wp2, WHp2, 393216);
  cast(Ws1, WHs1, 294912);
  cast(Ws2, WHs2, 294912);
  btab1_k<<<2912, 256, 0, stream>>>(abias, T1);
  btab2_k<<<448, 256, 0, stream>>>(sbias, T2);
  cast(x, Xh, 12845056);

  for (int l = 0; l < 4; ++l) {
    gemm_k<0, 0, 0, 1><<<392 * 4, 256, 0, stream>>>(
        Xh, WHqkv + l * 131072, qkvs + l * 512, qkvt + l * 512,
        nullptr, nullptr, QKVh, 50176, 512, 256);
    attn_mfma_k<<<1024, 256, 0, stream>>>(QKVh, T1 + l * 186368, Oh);
    gemm_k<0, 1, 1, 1><<<392 * 2, 256, 0, stream>>>(
        Oh, WHproj + l * 65536, projs + l * 256, projt + l * 256,
        (l == 0 ? x : X), X, Xh, 50176, 256, 256);
    gemm_k<1, 0, 0, 1><<<392 * 4, 256, 0, stream>>>(
        Xh, WH1 + l * 131072, m1s + l * 512, m1t + l * 512,
        nullptr, nullptr, Hh, 50176, 512, 256);
    gemm_k<0, 1, 1, 1><<<392 * 2, 256, 0, stream>>>(
        Hh, WH2 + l * 131072, m2s + l * 256, m2t + l * 256,
        X, X, Xh, 50176, 256, 512);
  }
  gemm_k<0, 0, 0, 1><<<392 * 10, 256, 0, stream>>>(
      Xh, WHkv, kvs, kvt, nullptr, nullptr, KVh, 50176, 1280, 256);
  gather_k<<<1568, 256, 0, stream>>>(Xh, Xqh);
  gemm_k<0, 0, 0, 1><<<98 * 2, 256, 0, stream>>>(
      Xqh, WHq, qss, qst, nullptr, nullptr, Qh, 12544, 256, 256);
  subattn_mfma_k<<<2048, 256, 0, stream>>>(KVh, Qh, T2, O2h);
  gemm_k<0, 0, 1, 1><<<98 * 3, 256, 0, stream>>>(
      O2h, WHp2, p2s, p2t, nullptr, X2, X2h, 12544, 384, 1024);
  gemm_k<1, 0, 0, 1><<<98 * 6, 256, 0, stream>>>(
      X2h, WHs1, s1s, s1t, nullptr, nullptr, H2h, 12544, 768, 384);
  gemm_k<0, 1, 1, 0><<<98 * 3, 256, 0, stream>>>(
      H2h, WHs2, s2s, s2t, X2, (float*)d_out, nullptr, 12544, 384, 768);
}